// Round 13
// baseline (261.331 us; speedup 1.0000x reference)
//
#include <hip/hip_runtime.h>
#include <hip/hip_fp16.h>
#include <cstdint>
#include <cstddef>

// Problem constants
#define NB 512
#define NR 1152
#define NC 8
#define NJ 10
#define NO 16
#define NJO 160   // NJ*NO
#define KSP 18    // r-splits for the s0 partial (64 r each)

typedef unsigned int uint32;

union H2U { __half2 h; uint32 u; };

__device__ __forceinline__ uint32 packf16(float a0, float a1) {
    H2U p;
    p.h = __halves2half2(__float2half_rn(a0), __float2half_rn(a1));
    return p.u;
}
__device__ __forceinline__ float2 unpackf16(uint32 w) {
    H2U p; p.u = w;
    return __half22float2(p.h);
}

// ============================================================================
// Kernel 0: transpose x[b][r][c] -> xT[r][b][c] so uhat can stage x coalesced.
// ============================================================================
__global__ __launch_bounds__(256) void xpose_kernel(const float* __restrict__ x,
                                                    float* __restrict__ xT) {
    const int r0 = blockIdx.x * 16;
    const int b0 = blockIdx.y * 64;
    const int t  = threadIdx.x;
    __shared__ float tile[16][65][8];

    for (int i = t; i < 2048; i += 256) {
        int b = i >> 5, r = (i >> 1) & 15, h = i & 1;
        float4 v = *(const float4*)&x[(size_t)(b0 + b) * (NR * NC) + (size_t)(r0 + r) * NC + h * 4];
        *(float4*)&tile[r][b][h * 4] = v;
    }
    __syncthreads();
    for (int i = t; i < 2048; i += 256) {
        int r = i >> 7, b = (i >> 1) & 63, h = i & 1;
        float4 v = *(const float4*)&tile[r][b][h * 4];
        *(float4*)&xT[(size_t)(r0 + r) * (NB * NC) + (size_t)(b0 + b) * NC + h * 4] = v;
    }
}

// ============================================================================
// Kernel 1: u_hat -> f16 pairs (quad-blocked row layout, same as R9) PLUS
// fp32 per-K-split partial of s0 = sum_r u (iter-0 needs no softmax).
// Re-tiled: block = (64 r x 32 b), grid (KSP=18, 16), 320 threads.
// Thread owns slot ni (f16 pair = 2 jo's) x 8 b's, FIXED across the block's
// 64 r -> s0 partial accumulates in 16 registers; no atomics anywhere.
// W rows read straight from global (16 consecutive floats per thread per r;
// 4x intra-wave redundancy served by L1; W is L3-resident).
// Row layout (must match routing): slot ni = qt*20 + 2*j + d  <->  f16 pair
// (o = 4qt+2d, 4qt+2d+1) of capsule j, i.e. jo0 = 16j + 4qt + 2d.
// ============================================================================
__global__ __launch_bounds__(320) void uhat_s0_kernel(const float* __restrict__ xT,
                                                      const float* __restrict__ W,
                                                      uint32* __restrict__ u,
                                                      float* __restrict__ part) {
    const int r0 = blockIdx.x * 64;
    const int b0 = blockIdx.y * 32;
    const int t  = threadIdx.x;

    const int ni = t % 80;
    const int bg = t / 80;              // 0..3
    const int qt  = ni / 20;
    const int rem = ni % 20;
    const int j   = rem >> 1;
    const int d   = rem & 1;
    const int jo0 = 16 * j + 4 * qt + 2 * d;   // even -> W rows jo0, jo0+1 = 16 floats

    __shared__ float xs[32][8];

    float sacc[8][2];
#pragma unroll
    for (int k = 0; k < 8; ++k) { sacc[k][0] = 0.0f; sacc[k][1] = 0.0f; }

#pragma unroll 1
    for (int rr = 0; rr < 64; ++rr) {
        const int r = r0 + rr;
        __syncthreads();
        if (t < 64) {
            int bb = t >> 1, h = t & 1;
            *(float4*)&xs[bb][h * 4] =
                *(const float4*)&xT[(size_t)r * (NB * NC) + (b0 + bb) * 8 + h * 4];
        }
        __syncthreads();

        const float4* wp = (const float4*)&W[(size_t)r * (NJO * NC) + jo0 * 8];
        float4 w0a = wp[0], w0b = wp[1], w1a = wp[2], w1b = wp[3];

#pragma unroll
        for (int k = 0; k < 8; ++k) {
            const int bl = bg + 4 * k;
            const float4* xp = (const float4*)xs[bl];
            float4 xa = xp[0], xb = xp[1];
            float a0 = w0a.x * xa.x + w0a.y * xa.y + w0a.z * xa.z + w0a.w * xa.w
                     + w0b.x * xb.x + w0b.y * xb.y + w0b.z * xb.z + w0b.w * xb.w;
            float a1 = w1a.x * xa.x + w1a.y * xa.y + w1a.z * xa.z + w1a.w * xa.w
                     + w1b.x * xb.x + w1b.y * xb.y + w1b.z * xb.z + w1b.w * xb.w;
            u[((size_t)(b0 + bl) * NR + r) * 80 + ni] = packf16(a0, a1);
            sacc[k][0] += a0;
            sacc[k][1] += a1;
        }
    }

    // write s0 partial: part[kx][b][jo]
    float* pb = part + (size_t)blockIdx.x * (NB * NJO);
#pragma unroll
    for (int k = 0; k < 8; ++k) {
        float* pp = pb + (size_t)(b0 + bg + 4 * k) * NJO + jo0;
        pp[0] = sacc[k][0];
        pp[1] = sacc[k][1];
    }
}

// ============================================================================
// Routing kernel: prologue reduces the 18 s0 partials (11.5 KB/block) ->
// squash -> v0; then TWO u-passes (iters 1,2) instead of three.
// Block = one b (576 thr, 9 waves). QUAD split (m = row-in-chunk, qt =
// o-quarter); lane loads 20 contiguous u32/row as 5 dwordx4. Softmax via
// quad DPP shuffles; acc[40] fp32; 4-stage reduce-scatter over the 16
// m-lanes; <=3 LDS atomics/lane; in-block squash. No global atomics.
// ============================================================================
__global__ __launch_bounds__(576, 2) void routing_kernel(const uint32* __restrict__ u,
                                                         const float* __restrict__ part,
                                                         float* __restrict__ outp) {
    const int b  = blockIdx.x;
    const int t  = threadIdx.x;
    const int w  = t >> 6;        // wave 0..8
    const int l  = t & 63;
    const int m  = (l >> 2) & 15; // row within chunk
    const int qt = l & 3;         // o-quarter

    __shared__ float sl[NJO];     // s accumulator
    __shared__ float vls[NJO];    // current v-sum (fp32), read by dot
    __shared__ float vaccl[NJO];  // running v0+v1 (fp32)

    // ---- prologue: s0 = 0.1 * sum_k part[k][b][:] ----
    if (t < NJO) {
        float s = 0.0f;
#pragma unroll
        for (int k = 0; k < KSP; ++k) s += part[(size_t)k * (NB * NJO) + b * NJO + t];
        sl[t] = 0.1f * s;
    }
    __syncthreads();

    // squash s0 -> v0; init vaccl = vls = v0
    if (t < 80) {
        float2 sv = *(const float2*)&sl[2 * t];
        float sq = sv.x * sv.x + sv.y * sv.y;
#pragma unroll
        for (int off = 1; off < 8; off <<= 1) sq += __shfl_xor(sq, off, 8);
        float scale = (sq / (1.0f + sq)) * rsqrtf(sq + 1e-8f);
        float2 va = make_float2(sv.x * scale, sv.y * scale);
        *(float2*)&vaccl[2 * t] = va;
        *(float2*)&vls[2 * t]   = va;
    }
    __syncthreads();

    const uint32* ubase = u + (size_t)b * (NR * 80) + qt * 20;

#pragma unroll 1
    for (int it = 1; it < 3; ++it) {
        // zero s tile
        for (int i = t; i < NJO; i += 576) sl[i] = 0.0f;
        __syncthreads();

        float acc[40];
#pragma unroll
        for (int i = 0; i < 40; ++i) acc[i] = 0.0f;

#pragma unroll 1
        for (int c8 = 0; c8 < 8; ++c8) {
            const int r = (w * 8 + c8) * 16 + m;
            const uint4* up = (const uint4*)(ubase + (size_t)r * 80);
            uint32 ur[20];
#pragma unroll
            for (int i = 0; i < 5; ++i) {
                uint4 q = up[i];
                ur[4 * i + 0] = q.x; ur[4 * i + 1] = q.y;
                ur[4 * i + 2] = q.z; ur[4 * i + 3] = q.w;
            }

            float cj[NJ];
            {
                float sum = 0.0f;
#pragma unroll
                for (int j = 0; j < NJ; ++j) {
                    float2 ua = unpackf16(ur[2 * j]);
                    float2 ub = unpackf16(ur[2 * j + 1]);
                    float4 vv = *(const float4*)&vls[16 * j + 4 * qt];
                    float pj = ua.x * vv.x + ua.y * vv.y + ub.x * vv.z + ub.y * vv.w;
                    pj += __shfl_xor(pj, 1);   // combine o-quarters (DPP)
                    pj += __shfl_xor(pj, 2);
                    float e = __expf(pj);      // |b_ij| <~ 70: safe in fp32
                    cj[j] = e;
                    sum += e;
                }
                float inv = 1.0f / sum;
#pragma unroll
                for (int j = 0; j < NJ; ++j) cj[j] *= inv;
            }

#pragma unroll
            for (int j = 0; j < NJ; ++j) {
                float2 ua = unpackf16(ur[2 * j]);
                float2 ub = unpackf16(ur[2 * j + 1]);
                acc[4 * j + 0] += cj[j] * ua.x;
                acc[4 * j + 1] += cj[j] * ua.y;
                acc[4 * j + 2] += cj[j] * ub.x;
                acc[4 * j + 3] += cj[j] * ub.y;
            }
        }

        // ---- reduce-scatter among the 16 same-qt lanes (masks 4,8,16,32) ----
        float a[24];
        {
            const int bit = (l >> 2) & 1;
#pragma unroll
            for (int i = 0; i < 24; ++i) {
                float lo = acc[i];
                float hi = (i + 24 < 40) ? acc[i + 24] : 0.0f;
                float send = bit ? lo : hi;
                float recv = __shfl_xor(send, 4);
                a[i] = (bit ? hi : lo) + recv;
            }
        }
#pragma unroll
        for (int st = 1; st < 4; ++st) {
            const int h = 24 >> st;              // 12,6,3
            const int bit = (l >> (2 + st)) & 1;
#pragma unroll
            for (int i = 0; i < 12; ++i) {
                if (i < h) {
                    float send = bit ? a[i] : a[i + h];
                    float recv = __shfl_xor(send, 4 << st);
                    a[i] = (bit ? a[i + h] : a[i]) + recv;
                }
            }
        }
        const int base = 3 * (__brev((uint32)m) >> 28);
#pragma unroll
        for (int i = 0; i < 3; ++i) {
            int aidx = base + i;
            if (aidx < 40) {
                int j = aidx >> 2, e = aidx & 3;
                atomicAdd(&sl[16 * j + 4 * qt + e], a[i]);
            }
        }
        __syncthreads();

        // ---- in-block squash: thread p<80 owns o-pair (2p, 2p+1) ----
        if (t < 80) {
            float2 sv = *(const float2*)&sl[2 * t];
            float sq = sv.x * sv.x + sv.y * sv.y;
#pragma unroll
            for (int off = 1; off < 8; off <<= 1) sq += __shfl_xor(sq, off, 8);
            float scale = (sq / (1.0f + sq)) * rsqrtf(sq + 1e-8f);
            float vx = sv.x * scale, vy = sv.y * scale;
            if (it == 2) {
                *(float2*)&outp[b * NJO + 2 * t] = make_float2(vx, vy);
            } else {
                float2 va = *(const float2*)&vaccl[2 * t];
                va.x += vx; va.y += vy;
                *(float2*)&vaccl[2 * t] = va;
                *(float2*)&vls[2 * t]   = va;
            }
        }
        __syncthreads();
    }
}

// ============================================================================
extern "C" void kernel_launch(void* const* d_in, const int* in_sizes, int n_in,
                              void* d_out, int out_size, void* d_ws, size_t ws_size,
                              hipStream_t stream) {
    (void)in_sizes; (void)n_in; (void)out_size; (void)ws_size;

    const float* x = (const float*)d_in[0];  // [B,R,C]
    const float* W = (const float*)d_in[1];  // [R,J,O,C]
    float* out = (float*)d_out;              // [B,J,O,1] fp32

    char* ws = (char*)d_ws;
    const size_t XBYTES = (size_t)NR * NB * NC * 4;    // 18,874,368
    const size_t UBYTES = (size_t)NB * NR * 80 * 4;    // 188,743,680 (f16 pairs)
    float*  xT   = (float*)ws;
    uint32* u    = (uint32*)(ws + XBYTES);             // [B,R,80] f16 pairs
    float*  part = (float*)(ws + XBYTES + UBYTES);     // [KSP][B][160] fp32

    xpose_kernel<<<dim3(NR / 16, NB / 64), 256, 0, stream>>>(x, xT);
    uhat_s0_kernel<<<dim3(KSP, NB / 32), 320, 0, stream>>>(xT, W, u, part);
    routing_kernel<<<NB, 576, 0, stream>>>(u, part, out);
}